// Round 5
// baseline (180.114 us; speedup 1.0000x reference)
//
#include <hip/hip_runtime.h>

#define BB 16
#define CC 128
#define TT 128
#define HH 128
#define BC (BB*CC)   // 2048

typedef __attribute__((ext_vector_type(8))) short bf16x8;
typedef __attribute__((ext_vector_type(4))) float f32x4;

__device__ __forceinline__ unsigned short f2bf(float f) {
  union { float f; unsigned u; } v; v.f = f;
  unsigned u = v.u;
  u += 0x7FFFu + ((u >> 16) & 1u);   // round-to-nearest-even
  return (unsigned short)(u >> 16);
}

__device__ __forceinline__ bf16x8 pack8(f32x4 a, f32x4 b) {
  bf16x8 r;
  r[0] = (short)f2bf(a[0]); r[1] = (short)f2bf(a[1]);
  r[2] = (short)f2bf(a[2]); r[3] = (short)f2bf(a[3]);
  r[4] = (short)f2bf(b[0]); r[5] = (short)f2bf(b[1]);
  r[6] = (short)f2bf(b[2]); r[7] = (short)f2bf(b[3]);
  return r;
}

__device__ __forceinline__ f32x4 ntload(const float* p) {
  return __builtin_nontemporal_load((const f32x4*)p);
}

// ---- prep: weights (blk 0..55) + bias rows (blk 56..311) + mask compaction (blk 312)
// Weight fragments fragment-major: frag f = kt*8+n, lane l, elem e:
//   value = W_src[k][ncol],  ncol = n*16 + (l&15),  k = kt*32 + (l>>4)*8 + e
__global__ __launch_bounds__(256) void prep_kernel(
    const float* __restrict__ Wt, const float* __restrict__ Wc, const float* __restrict__ Wa,
    const float* __restrict__ clone, const float* __restrict__ food,
    const float* __restrict__ bt, const float* __restrict__ bcl,
    const int* __restrict__ tmask, const int* __restrict__ cmask,
    unsigned short* __restrict__ W2sw, unsigned short* __restrict__ Wcsw,
    unsigned short* __restrict__ WaggT,
    float* __restrict__ cpt, float* __restrict__ cp1,
    unsigned short* __restrict__ agg,
    int* __restrict__ tidx, int* __restrict__ tcnt,
    int* __restrict__ cidx, int* __restrict__ ccnt) {
  const int blk = blockIdx.x, tid = threadIdx.x;
  if (blk < 56) {
    int i = blk * 256 + tid;
    if (i < 2048) {                       // thorn frags: 32 frags x 64 lanes
      int f = i >> 6, l = i & 63;
      int kt = f >> 3, n = f & 7;
      int ncol = n * 16 + (l & 15);
      int k0 = kt * 32 + (l >> 4) * 8;
      unsigned short o[8];
      #pragma unroll
      for (int e = 0; e < 8; ++e) o[e] = f2bf(Wt[(128 + k0 + e) * 128 + ncol]);
      *(uint4*)&W2sw[i * 8] = *(uint4*)o;
    } else if (i < 6144) {                // clone frags: 64 frags x 64 lanes
      int j = i - 2048;
      int f = j >> 6, l = j & 63;
      int kt = f >> 3, n = f & 7;
      int ncol = n * 16 + (l & 15);
      int lk8 = (l >> 4) * 8;
      unsigned short o[8];
      #pragma unroll
      for (int e = 0; e < 8; ++e) {
        int src = (kt < 4) ? (256 + kt * 32 + lk8 + e) : (128 + (kt - 4) * 32 + lk8 + e);
        o[e] = f2bf(Wc[src * 128 + ncol]);
      }
      *(uint4*)&Wcsw[j * 8] = *(uint4*)o;
    } else if (i < 14336) {               // agg weights, plain [n][k] transpose
      int j = i - 6144;                   // [0, 8192)
      int n = j >> 6, k0 = (j & 63) * 8;
      unsigned short o[8];
      #pragma unroll
      for (int e = 0; e < 8; ++e) o[e] = f2bf(Wa[(k0 + e) * 128 + n]);
      *(uint4*)&WaggT[n * 512 + k0] = *(uint4*)o;
    }
  } else if (blk < 312) {
    // bias rows: 8 bc rows per block; weight reads amortized 8x
    const int bc0 = (blk - 56) * 8;
    __shared__ float cl[8][128];
    for (int i = tid; i < 1024; i += 256) cl[i >> 7][i & 127] = clone[bc0 * 128 + i];
    __syncthreads();
    const int k = tid & 127, r0 = (tid >> 7) * 4;
    float s1[4], s2[4];
    #pragma unroll
    for (int r = 0; r < 4; ++r) { s1[r] = bt[k]; s2[r] = bcl[k]; }
    #pragma unroll 8
    for (int h = 0; h < 128; ++h) {
      float w1 = Wt[h * 128 + k], w2 = Wc[h * 128 + k];
      #pragma unroll
      for (int r = 0; r < 4; ++r) {
        float c = cl[r0 + r][h];
        s1[r] = fmaf(c, w1, s1[r]);
        s2[r] = fmaf(c, w2, s2[r]);
      }
    }
    #pragma unroll
    for (int r = 0; r < 4; ++r) {
      cpt[(bc0 + r0 + r) * 128 + k] = s1[r];
      cp1[(bc0 + r0 + r) * 128 + k] = s2[r];
    }
    for (int i = tid; i < 1024; i += 256) {
      int r = i >> 7, kk = i & 127;
      agg[(size_t)(bc0 + r) * 512 + kk]       = f2bf(cl[r][kk]);
      agg[(size_t)(bc0 + r) * 512 + 128 + kk] = f2bf(food[bc0 * 128 + i]);
    }
  } else {
    // mask compaction: thread i<32: b=i>>1, which=i&1; serial scan of 128 entries
    if (tid < 32) {
      int b = tid >> 1, which = tid & 1;
      const int* m = which ? cmask : tmask;
      int* idx = which ? cidx : tidx;
      int c = 0;
      for (int i = 0; i < 128; ++i)
        if (m[b * 128 + i]) idx[b * 128 + c++] = i;
      if (which) ccnt[b] = c; else tcnt[b] = c;
    }
  }
}

// ---- fused branch kernel: blocks 0..511 clone, 512..1023 thorn -------------
// Per block: 4 bc tiles (same b => same mask/count/index list).
// Active rows only (gathered); units = 4 tiles x ceil(cnt/16) row-groups,
// round-robined over 8 waves (wave stays on one tile). Epilogue max via LDS
// atomicMax on int-reinterpreted non-negative floats.
__global__ __launch_bounds__(512, 4) void branch4(
    const float* __restrict__ trel, const float* __restrict__ crel,
    const float* __restrict__ cloneA,
    const float* __restrict__ cpt, const float* __restrict__ cp1,
    const int* __restrict__ tidx, const int* __restrict__ tcnt,
    const int* __restrict__ cidx, const int* __restrict__ ccnt,
    const uint4* __restrict__ W2sw, const uint4* __restrict__ Wcsw,
    unsigned short* __restrict__ agg) {
  __shared__ uint4 Wlds[8 * 512];             // 64 KB
  __shared__ int redbuf[4][128];              // 2 KB
  __shared__ int idxl[128];
  __shared__ float biasl[4][128];             // 2 KB

  const bool isClone = blockIdx.x < 512;
  const int tileIdx = blockIdx.x & 511;
  const float* __restrict__ rel     = isClone ? crel  : trel;
  const float* __restrict__ biasrow = isClone ? cp1   : cpt;
  const int*   __restrict__ idxg    = isClone ? cidx  : tidx;
  const uint4* __restrict__ Wsw     = isClone ? Wcsw  : W2sw;
  const int aggoff = isClone ? 384 : 256;
  const int nkt    = isClone ? 8 : 4;

  const int tid = threadIdx.x;
  const int wave = tid >> 6, lane = tid & 63;
  const int l16 = lane & 15, lk = lane >> 4;
  const int bc0 = tileIdx << 2;
  const int b = bc0 >> 7;
  const int cnt = (isClone ? ccnt : tcnt)[b];

  for (int i = tid; i < nkt * 512; i += 512) Wlds[i] = Wsw[i];
  if (tid < 128) idxl[tid] = idxg[b * 128 + tid];
  ((int*)redbuf)[tid] = 0;                          // 512 = 4*128 exactly
  biasl[tid >> 7][tid & 127] = biasrow[bc0 * 128 + tid];
  __syncthreads();

  const int G = (cnt + 15) >> 4;
  const int units = G * 4;
  for (int u = wave; u < units; u += 8) {
    const int t = u & 3, g = u >> 2;
    const int bc = bc0 + t;
    const int rsel = g * 16 + l16;
    const int row = idxl[rsel < cnt ? rsel : cnt - 1];

    // gather-load this unit's A rows (f32 -> bf16 regs)
    const float* Ra = rel + ((size_t)bc * 128 + row) * 128 + lk * 8;
    bf16x8 afr[4];
    #pragma unroll
    for (int kt = 0; kt < 4; ++kt)
      afr[kt] = pack8(ntload(Ra + kt * 32), ntload(Ra + kt * 32 + 4));
    bf16x8 afc[4];
    if (isClone) {
      const float* Ca = cloneA + ((size_t)b * 128 + row) * 128 + lk * 8;
      #pragma unroll
      for (int kt = 0; kt < 4; ++kt)
        afc[kt] = pack8(*(const f32x4*)(Ca + kt * 32),
                        *(const f32x4*)(Ca + kt * 32 + 4));
    }

    f32x4 acc[8];
    #pragma unroll
    for (int n = 0; n < 8; ++n) acc[n] = (f32x4){0.f, 0.f, 0.f, 0.f};
    #pragma unroll
    for (int kt = 0; kt < 4; ++kt) {
      #pragma unroll
      for (int n = 0; n < 8; ++n) {
        bf16x8 bfr = *(const bf16x8*)&Wlds[(kt * 8 + n) * 64 + lane];
        acc[n] = __builtin_amdgcn_mfma_f32_16x16x32_bf16(afr[kt], bfr, acc[n], 0, 0, 0);
      }
    }
    if (isClone) {
      #pragma unroll
      for (int kt = 0; kt < 4; ++kt) {
        #pragma unroll
        for (int n = 0; n < 8; ++n) {
          bf16x8 bfr = *(const bf16x8*)&Wlds[((kt + 4) * 8 + n) * 64 + lane];
          acc[n] = __builtin_amdgcn_mfma_f32_16x16x32_bf16(afc[kt], bfr, acc[n], 0, 0, 0);
        }
      }
    }

    // epilogue: bias, relu, max over this unit's 16 rows, LDS atomic max
    #pragma unroll
    for (int n = 0; n < 8; ++n) {
      float bias = biasl[t][n * 16 + l16];
      float m0 = 0.f;
      #pragma unroll
      for (int j = 0; j < 4; ++j)
        m0 = fmaxf(m0, fmaxf(acc[n][j] + bias, 0.f));
      float v = fmaxf(m0, __shfl_xor(m0, 16));
      v = fmaxf(v, __shfl_xor(v, 32));
      if (lane < 16) atomicMax(&redbuf[t][n * 16 + lane], __float_as_int(v));
    }
  }
  __syncthreads();
  {
    int t = tid >> 7, col = tid & 127;
    agg[(size_t)(bc0 + t) * 512 + aggoff + col] =
        f2bf(__int_as_float(redbuf[t][col]));
  }
}

// ---- final: out = clone + relu(agg(2048x512) @ W_agg + b_agg) --------------
__global__ __launch_bounds__(256) void final_kernel(
    const unsigned short* __restrict__ agg, const unsigned short* __restrict__ WaggT,
    const float* __restrict__ clone, const float* __restrict__ bagg,
    float* __restrict__ out) {
  const int tid = threadIdx.x;
  const int wave = tid >> 6, lane = tid & 63;
  const int l16 = lane & 15, lk = lane >> 4;
  const int mrow = blockIdx.x * 16;

  f32x4 acc[2];
  acc[0] = (f32x4){0.f, 0.f, 0.f, 0.f};
  acc[1] = (f32x4){0.f, 0.f, 0.f, 0.f};
  #pragma unroll
  for (int kt = 0; kt < 16; ++kt) {
    bf16x8 a = *(const bf16x8*)(agg + (size_t)(mrow + l16) * 512 + kt * 32 + lk * 8);
    #pragma unroll
    for (int nn = 0; nn < 2; ++nn) {
      int ncol = (wave * 2 + nn) * 16 + l16;
      bf16x8 bfr = *(const bf16x8*)(WaggT + (size_t)ncol * 512 + kt * 32 + lk * 8);
      acc[nn] = __builtin_amdgcn_mfma_f32_16x16x32_bf16(a, bfr, acc[nn], 0, 0, 0);
    }
  }
  #pragma unroll
  for (int nn = 0; nn < 2; ++nn) {
    int col = (wave * 2 + nn) * 16 + l16;
    float bias = bagg[col];
    #pragma unroll
    for (int j = 0; j < 4; ++j) {
      int row = mrow + lk * 4 + j;
      out[row * 128 + col] = clone[row * 128 + col] + fmaxf(acc[nn][j] + bias, 0.f);
    }
  }
}

extern "C" void kernel_launch(void* const* d_in, const int* in_sizes, int n_in,
                              void* d_out, int out_size, void* d_ws, size_t ws_size,
                              hipStream_t stream) {
  const float* food  = (const float*)d_in[0];
  const float* trel  = (const float*)d_in[1];
  const float* clone = (const float*)d_in[2];
  const float* crel  = (const float*)d_in[3];
  const int*   tmask = (const int*)d_in[4];
  const int*   cmask = (const int*)d_in[5];
  const float* Wt    = (const float*)d_in[6];
  const float* bt    = (const float*)d_in[7];
  const float* Wc    = (const float*)d_in[8];
  const float* bcl   = (const float*)d_in[9];
  const float* Wa    = (const float*)d_in[10];
  const float* ba    = (const float*)d_in[11];
  float* out = (float*)d_out;

  char* w = (char*)d_ws;
  float* cpt = (float*)w;                      w += (size_t)BC * 128 * 4;
  float* cp1 = (float*)w;                      w += (size_t)BC * 128 * 4;
  unsigned short* W2sw  = (unsigned short*)w;  w += 32 * 64 * 8 * 2;     // 32 KB
  unsigned short* Wcsw  = (unsigned short*)w;  w += 64 * 64 * 8 * 2;     // 64 KB
  unsigned short* WaggT = (unsigned short*)w;  w += 128 * 512 * 2;       // 128 KB
  unsigned short* aggb  = (unsigned short*)w;  w += (size_t)BC * 512 * 2;
  int* tidx = (int*)w;                         w += 16 * 128 * 4;
  int* cidx = (int*)w;                         w += 16 * 128 * 4;
  int* tcnt = (int*)w;                         w += 16 * 4;
  int* ccnt = (int*)w;                         w += 16 * 4;

  prep_kernel<<<313, 256, 0, stream>>>(Wt, Wc, Wa, clone, food, bt, bcl,
                                       tmask, cmask,
                                       W2sw, Wcsw, WaggT, cpt, cp1, aggb,
                                       tidx, tcnt, cidx, ccnt);
  branch4<<<1024, 512, 0, stream>>>(trel, crel, clone, cpt, cp1,
                                    tidx, tcnt, cidx, ccnt,
                                    (const uint4*)W2sw, (const uint4*)Wcsw, aggb);
  final_kernel<<<128, 256, 0, stream>>>(aggb, WaggT, clone, ba, out);
}

// Round 6
// 73.935 us; speedup vs baseline: 2.4361x; 2.4361x over previous
//
#include <hip/hip_runtime.h>

#define BB 16
#define CC 128
#define TT 128
#define HH 128
#define BC (BB*CC)   // 2048

typedef __attribute__((ext_vector_type(8))) short bf16x8;
typedef __attribute__((ext_vector_type(4))) float f32x4;

__device__ __forceinline__ unsigned short f2bf(float f) {
  union { float f; unsigned u; } v; v.f = f;
  unsigned u = v.u;
  u += 0x7FFFu + ((u >> 16) & 1u);   // round-to-nearest-even
  return (unsigned short)(u >> 16);
}

__device__ __forceinline__ bf16x8 pack8(f32x4 a, f32x4 b) {
  bf16x8 r;
  r[0] = (short)f2bf(a[0]); r[1] = (short)f2bf(a[1]);
  r[2] = (short)f2bf(a[2]); r[3] = (short)f2bf(a[3]);
  r[4] = (short)f2bf(b[0]); r[5] = (short)f2bf(b[1]);
  r[6] = (short)f2bf(b[2]); r[7] = (short)f2bf(b[3]);
  return r;
}

// ---- prep: weights (blk 0..55) + bias rows (blk 56..311) + mask compaction (blk 312)
// Weight fragments fragment-major: frag f = kt*8+n, lane l, elem e:
//   value = W_src[k][ncol],  ncol = n*16 + (l&15),  k = kt*32 + (l>>4)*8 + e
__global__ __launch_bounds__(256) void prep_kernel(
    const float* __restrict__ Wt, const float* __restrict__ Wc, const float* __restrict__ Wa,
    const float* __restrict__ clone, const float* __restrict__ food,
    const float* __restrict__ bt, const float* __restrict__ bcl,
    const int* __restrict__ tmask, const int* __restrict__ cmask,
    unsigned short* __restrict__ W2sw, unsigned short* __restrict__ Wcsw,
    unsigned short* __restrict__ WaggT,
    float* __restrict__ cpt, float* __restrict__ cp1,
    unsigned short* __restrict__ agg,
    int* __restrict__ tidx, int* __restrict__ tcnt,
    int* __restrict__ cidx, int* __restrict__ ccnt) {
  const int blk = blockIdx.x, tid = threadIdx.x;
  if (blk < 56) {
    int i = blk * 256 + tid;
    if (i < 2048) {                       // thorn frags: 32 frags x 64 lanes
      int f = i >> 6, l = i & 63;
      int kt = f >> 3, n = f & 7;
      int ncol = n * 16 + (l & 15);
      int k0 = kt * 32 + (l >> 4) * 8;
      unsigned short o[8];
      #pragma unroll
      for (int e = 0; e < 8; ++e) o[e] = f2bf(Wt[(128 + k0 + e) * 128 + ncol]);
      *(uint4*)&W2sw[i * 8] = *(uint4*)o;
    } else if (i < 6144) {                // clone frags: 64 frags x 64 lanes
      int j = i - 2048;
      int f = j >> 6, l = j & 63;
      int kt = f >> 3, n = f & 7;
      int ncol = n * 16 + (l & 15);
      int lk8 = (l >> 4) * 8;
      unsigned short o[8];
      #pragma unroll
      for (int e = 0; e < 8; ++e) {
        int src = (kt < 4) ? (256 + kt * 32 + lk8 + e) : (128 + (kt - 4) * 32 + lk8 + e);
        o[e] = f2bf(Wc[src * 128 + ncol]);
      }
      *(uint4*)&Wcsw[j * 8] = *(uint4*)o;
    } else if (i < 14336) {               // agg weights, plain [n][k] transpose
      int j = i - 6144;                   // [0, 8192)
      int n = j >> 6, k0 = (j & 63) * 8;
      unsigned short o[8];
      #pragma unroll
      for (int e = 0; e < 8; ++e) o[e] = f2bf(Wa[(k0 + e) * 128 + n]);
      *(uint4*)&WaggT[n * 512 + k0] = *(uint4*)o;
    }
  } else if (blk < 312) {
    // bias rows: 8 bc rows per block; weight reads amortized 8x
    const int bc0 = (blk - 56) * 8;
    __shared__ float cl[8][128];
    for (int i = tid; i < 1024; i += 256) cl[i >> 7][i & 127] = clone[bc0 * 128 + i];
    __syncthreads();
    const int k = tid & 127, r0 = (tid >> 7) * 4;
    float s1[4], s2[4];
    #pragma unroll
    for (int r = 0; r < 4; ++r) { s1[r] = bt[k]; s2[r] = bcl[k]; }
    #pragma unroll 8
    for (int h = 0; h < 128; ++h) {
      float w1 = Wt[h * 128 + k], w2 = Wc[h * 128 + k];
      #pragma unroll
      for (int r = 0; r < 4; ++r) {
        float c = cl[r0 + r][h];
        s1[r] = fmaf(c, w1, s1[r]);
        s2[r] = fmaf(c, w2, s2[r]);
      }
    }
    #pragma unroll
    for (int r = 0; r < 4; ++r) {
      cpt[(bc0 + r0 + r) * 128 + k] = s1[r];
      cp1[(bc0 + r0 + r) * 128 + k] = s2[r];
    }
    for (int i = tid; i < 1024; i += 256) {
      int r = i >> 7, kk = i & 127;
      agg[(size_t)(bc0 + r) * 512 + kk]       = f2bf(cl[r][kk]);
      agg[(size_t)(bc0 + r) * 512 + 128 + kk] = f2bf(food[bc0 * 128 + i]);
    }
  } else {
    // mask compaction: thread i<32: b=i>>1, which=i&1; serial scan of 128 entries
    if (tid < 32) {
      int b = tid >> 1, which = tid & 1;
      const int* m = which ? cmask : tmask;
      int* idx = which ? cidx : tidx;
      int c = 0;
      for (int i = 0; i < 128; ++i)
        if (m[b * 128 + i]) idx[b * 128 + c++] = i;
      if (which) ccnt[b] = c; else tcnt[b] = c;
    }
  }
}

// ---- fused branch kernel: blocks 0..255 clone, 256..511 thorn --------------
// branch3 skeleton (static loop, 1-deep reg prefetch, shfl+redbuf epilogue),
// 8 bc tiles per block, rows GATHERED through the compacted mask index list
// (same b => same list for all 8 tiles). Waves past cnt duplicate the last
// active row: loads are cache hits, max is idempotent. No mask multiply.
__global__ __launch_bounds__(512, 4) void branch5(
    const float* __restrict__ trel, const float* __restrict__ crel,
    const float* __restrict__ cloneA,
    const float* __restrict__ cpt, const float* __restrict__ cp1,
    const int* __restrict__ tidx, const int* __restrict__ tcnt,
    const int* __restrict__ cidx, const int* __restrict__ ccnt,
    const uint4* __restrict__ W2sw, const uint4* __restrict__ Wcsw,
    unsigned short* __restrict__ agg) {
  __shared__ uint4 Wlds[8 * 512];             // 64 KB
  __shared__ float redbuf[2][8][128];         // 8 KB, double-buffered
  __shared__ int idxl[128];
  __shared__ float biasl[8][128];             // 4 KB

  const bool isClone = blockIdx.x < 256;
  const int tileIdx = blockIdx.x & 255;
  const float* __restrict__ rel     = isClone ? crel  : trel;
  const float* __restrict__ biasrow = isClone ? cp1   : cpt;
  const int*   __restrict__ idxg    = isClone ? cidx  : tidx;
  const uint4* __restrict__ Wsw     = isClone ? Wcsw  : W2sw;
  const int aggoff = isClone ? 384 : 256;
  const int nkt    = isClone ? 8 : 4;

  const int tid = threadIdx.x;
  const int wave = tid >> 6, lane = tid & 63;
  const int l16 = lane & 15, lk = lane >> 4;
  const int bc0 = tileIdx << 3;               // 8 tiles per block
  const int b = bc0 >> 7;                     // same b for all 8 tiles
  const int cnt = (isClone ? ccnt : tcnt)[b];

  for (int i = tid; i < nkt * 512; i += 512) Wlds[i] = Wsw[i];
  if (tid < 128) idxl[tid] = idxg[b * 128 + tid];
  #pragma unroll
  for (int i = 0; i < 2; ++i)
    biasl[(i * 512 + tid) >> 7][(i * 512 + tid) & 127] = biasrow[bc0 * 128 + i * 512 + tid];
  __syncthreads();                            // W, idx, bias ready

  // gathered A row for this lane (same for all 8 tiles)
  int rsel = wave * 16 + l16;
  rsel = rsel < cnt ? rsel : (cnt > 0 ? cnt - 1 : 0);
  const int row = (cnt > 0) ? idxl[rsel] : 0;

  // clone branch: K-extension fragments from clone[b] at the SAME gathered rows
  bf16x8 afc[4];
  if (isClone) {
    const float* Ca = cloneA + ((size_t)b * 128 + row) * 128 + lk * 8;
    #pragma unroll
    for (int kt = 0; kt < 4; ++kt)
      afc[kt] = pack8(*(const f32x4*)(Ca + kt * 32),
                      *(const f32x4*)(Ca + kt * 32 + 4));
  }

  // prefetch tile 0 (f32 in regs)
  const float* Rbase = rel + ((size_t)bc0 * 128 + row) * 128 + lk * 8;
  f32x4 pf[4][2];
  #pragma unroll
  for (int kt = 0; kt < 4; ++kt) {
    pf[kt][0] = *(const f32x4*)(Rbase + kt * 32);
    pf[kt][1] = *(const f32x4*)(Rbase + kt * 32 + 4);
  }

  for (int t = 0; t < 8; ++t) {
    const int bc = bc0 + t;

    bf16x8 afr[4];
    #pragma unroll
    for (int kt = 0; kt < 4; ++kt) afr[kt] = pack8(pf[kt][0], pf[kt][1]);

    // issue next tile's loads: they fly during MFMA + epilogue
    if (t < 7) {
      const float* Rn = Rbase + (size_t)(t + 1) * 16384;
      #pragma unroll
      for (int kt = 0; kt < 4; ++kt) {
        pf[kt][0] = *(const f32x4*)(Rn + kt * 32);
        pf[kt][1] = *(const f32x4*)(Rn + kt * 32 + 4);
      }
    }

    f32x4 acc[8];
    #pragma unroll
    for (int n = 0; n < 8; ++n) acc[n] = (f32x4){0.f, 0.f, 0.f, 0.f};
    #pragma unroll
    for (int kt = 0; kt < 4; ++kt) {
      #pragma unroll
      for (int n = 0; n < 8; ++n) {
        bf16x8 bfr = *(const bf16x8*)&Wlds[(kt * 8 + n) * 64 + lane];
        acc[n] = __builtin_amdgcn_mfma_f32_16x16x32_bf16(afr[kt], bfr, acc[n], 0, 0, 0);
      }
    }
    if (isClone) {
      #pragma unroll
      for (int kt = 0; kt < 4; ++kt) {
        #pragma unroll
        for (int n = 0; n < 8; ++n) {
          bf16x8 bfr = *(const bf16x8*)&Wlds[((kt + 4) * 8 + n) * 64 + lane];
          acc[n] = __builtin_amdgcn_mfma_f32_16x16x32_bf16(afc[kt], bfr, acc[n], 0, 0, 0);
        }
      }
    }

    // epilogue: bias, relu, max over rows (mask handled by the gather)
    #pragma unroll
    for (int n = 0; n < 8; ++n) {
      float bias = biasl[t][n * 16 + l16];
      float m0 = 0.f;
      #pragma unroll
      for (int j = 0; j < 4; ++j)
        m0 = fmaxf(m0, fmaxf(acc[n][j] + bias, 0.f));
      float v = fmaxf(m0, __shfl_xor(m0, 16));
      v = fmaxf(v, __shfl_xor(v, 32));
      if (lane < 16) redbuf[t & 1][wave][n * 16 + lane] = v;
    }
    __syncthreads();
    if (tid < 128) {
      float v = redbuf[t & 1][0][tid];
      #pragma unroll
      for (int w2 = 1; w2 < 8; ++w2) v = fmaxf(v, redbuf[t & 1][w2][tid]);
      agg[(size_t)bc * 512 + aggoff + tid] = f2bf(cnt > 0 ? v : 0.f);
    }
    // no second barrier: next tile writes the other redbuf half
  }
}

// ---- final: out = clone + relu(agg(2048x512) @ W_agg + b_agg) --------------
__global__ __launch_bounds__(256) void final_kernel(
    const unsigned short* __restrict__ agg, const unsigned short* __restrict__ WaggT,
    const float* __restrict__ clone, const float* __restrict__ bagg,
    float* __restrict__ out) {
  const int tid = threadIdx.x;
  const int wave = tid >> 6, lane = tid & 63;
  const int l16 = lane & 15, lk = lane >> 4;
  const int mrow = blockIdx.x * 16;

  f32x4 acc[2];
  acc[0] = (f32x4){0.f, 0.f, 0.f, 0.f};
  acc[1] = (f32x4){0.f, 0.f, 0.f, 0.f};
  #pragma unroll
  for (int kt = 0; kt < 16; ++kt) {
    bf16x8 a = *(const bf16x8*)(agg + (size_t)(mrow + l16) * 512 + kt * 32 + lk * 8);
    #pragma unroll
    for (int nn = 0; nn < 2; ++nn) {
      int ncol = (wave * 2 + nn) * 16 + l16;
      bf16x8 bfr = *(const bf16x8*)(WaggT + (size_t)ncol * 512 + kt * 32 + lk * 8);
      acc[nn] = __builtin_amdgcn_mfma_f32_16x16x32_bf16(a, bfr, acc[nn], 0, 0, 0);
    }
  }
  #pragma unroll
  for (int nn = 0; nn < 2; ++nn) {
    int col = (wave * 2 + nn) * 16 + l16;
    float bias = bagg[col];
    #pragma unroll
    for (int j = 0; j < 4; ++j) {
      int row = mrow + lk * 4 + j;
      out[row * 128 + col] = clone[row * 128 + col] + fmaxf(acc[nn][j] + bias, 0.f);
    }
  }
}

extern "C" void kernel_launch(void* const* d_in, const int* in_sizes, int n_in,
                              void* d_out, int out_size, void* d_ws, size_t ws_size,
                              hipStream_t stream) {
  const float* food  = (const float*)d_in[0];
  const float* trel  = (const float*)d_in[1];
  const float* clone = (const float*)d_in[2];
  const float* crel  = (const float*)d_in[3];
  const int*   tmask = (const int*)d_in[4];
  const int*   cmask = (const int*)d_in[5];
  const float* Wt    = (const float*)d_in[6];
  const float* bt    = (const float*)d_in[7];
  const float* Wc    = (const float*)d_in[8];
  const float* bcl   = (const float*)d_in[9];
  const float* Wa    = (const float*)d_in[10];
  const float* ba    = (const float*)d_in[11];
  float* out = (float*)d_out;

  char* w = (char*)d_ws;
  float* cpt = (float*)w;                      w += (size_t)BC * 128 * 4;
  float* cp1 = (float*)w;                      w += (size_t)BC * 128 * 4;
  unsigned short* W2sw  = (unsigned short*)w;  w += 32 * 64 * 8 * 2;     // 32 KB
  unsigned short* Wcsw  = (unsigned short*)w;  w += 64 * 64 * 8 * 2;     // 64 KB
  unsigned short* WaggT = (unsigned short*)w;  w += 128 * 512 * 2;       // 128 KB
  unsigned short* aggb  = (unsigned short*)w;  w += (size_t)BC * 512 * 2;
  int* tidx = (int*)w;                         w += 16 * 128 * 4;
  int* cidx = (int*)w;                         w += 16 * 128 * 4;
  int* tcnt = (int*)w;                         w += 16 * 4;
  int* ccnt = (int*)w;                         w += 16 * 4;

  prep_kernel<<<313, 256, 0, stream>>>(Wt, Wc, Wa, clone, food, bt, bcl,
                                       tmask, cmask,
                                       W2sw, Wcsw, WaggT, cpt, cp1, aggb,
                                       tidx, tcnt, cidx, ccnt);
  branch5<<<512, 512, 0, stream>>>(trel, crel, clone, cpt, cp1,
                                   tidx, tcnt, cidx, ccnt,
                                   (const uint4*)W2sw, (const uint4*)Wcsw, aggb);
  final_kernel<<<128, 256, 0, stream>>>(aggb, WaggT, clone, ba, out);
}